// Round 1
// baseline (280.520 us; speedup 1.0000x reference)
//
#include <hip/hip_runtime.h>
#include <hip/hip_bf16.h>
#include <stdint.h>

// B=2, T=2048, C=1024, H=16, D=64
// out = ( causal_attn(x@Wqkv) ) @ Wout
// bf16 MFMA pipeline, f32 accumulate everywhere.

#define Bv 2
#define Tv 2048
#define Cv 1024
#define Hv 16
#define Dv 64
#define Mv 4096  // B*T

typedef __attribute__((ext_vector_type(8))) __bf16 bf16x8;
typedef __attribute__((ext_vector_type(4))) float f32x4;
typedef __attribute__((ext_vector_type(4))) unsigned short ushort4v;

__device__ __forceinline__ unsigned short f2bf(float f) {
  union { float f; unsigned int u; } v; v.f = f;
  unsigned int r = (v.u + 0x7FFFu + ((v.u >> 16) & 1u)) >> 16;  // RNE
  return (unsigned short)r;
}

__device__ __forceinline__ void gload16(const void* g, void* l) {
  __builtin_amdgcn_global_load_lds(
      (__attribute__((address_space(1))) void*)(uintptr_t)g,
      (__attribute__((address_space(3))) void*)(unsigned int)(uintptr_t)l,
      16, 0, 0);
}

__device__ __forceinline__ bf16x8 ldfrag(const unsigned short* p) {
  return *reinterpret_cast<const bf16x8*>(p);
}

// ---------------- cast f32 -> bf16, 8 elems/thread ----------------
__global__ void __launch_bounds__(256) cast_bf16(const float* __restrict__ in,
                                                 unsigned short* __restrict__ out) {
  int i = (blockIdx.x * 256 + threadIdx.x) * 8;
  float4 a = *reinterpret_cast<const float4*>(in + i);
  float4 b = *reinterpret_cast<const float4*>(in + i + 4);
  ushort4v o0, o1;
  o0.x = f2bf(a.x); o0.y = f2bf(a.y); o0.z = f2bf(a.z); o0.w = f2bf(a.w);
  o1.x = f2bf(b.x); o1.y = f2bf(b.y); o1.z = f2bf(b.z); o1.w = f2bf(b.w);
  *reinterpret_cast<ushort4v*>(out + i) = o0;
  *reinterpret_cast<ushort4v*>(out + i + 4) = o1;
}

// ---------------- transpose + cast: in f32 [R][Cc] -> out bf16 [Cc][R] ----------------
__global__ void __launch_bounds__(256) transcast(const float* __restrict__ in,
                                                 unsigned short* __restrict__ out,
                                                 int R, int Cc) {
  __shared__ float tile[32][33];
  int c0 = blockIdx.x * 32;
  int r0 = blockIdx.y * 32;
  int tc = threadIdx.x & 31, tr = threadIdx.x >> 5;  // 8 rows x 32 cols per pass
#pragma unroll
  for (int i = 0; i < 4; i++)
    tile[tr + i * 8][tc] = in[(size_t)(r0 + tr + i * 8) * Cc + c0 + tc];
  __syncthreads();
#pragma unroll
  for (int i = 0; i < 4; i++)
    out[(size_t)(c0 + tr + i * 8) * R + r0 + tc] = f2bf(tile[tc][tr + i * 8]);
}

// ---------------- GEMM: C[M][N] = A[M][1024] * Bt[N][1024]^T ----------------
// 128x128 tile, BK=32, 256 threads (2x2 waves, each 64x64 = 4x4 MFMA frags).
// LDS chunk-major: [k-chunk of 8][row][8] -> linear global_load_lds dest AND
// conflict-free ds_read_b128 fragment reads.
// EPI 0: scatter qkv -> q[B,H,T,D], k[B,H,T,D], vT[B,H,D,T] (bf16)
// EPI 1: write f32 out[M][N]
template <int EPI>
__global__ void __launch_bounds__(256) gemm128(
    const unsigned short* __restrict__ A, const unsigned short* __restrict__ Bt,
    float* __restrict__ outF, unsigned short* __restrict__ qo,
    unsigned short* __restrict__ ko, unsigned short* __restrict__ vTo, int N) {
  __shared__ unsigned short la[4][128][8];
  __shared__ unsigned short lb[4][128][8];
  const int K = 1024;
  int mb = blockIdx.y * 128, nb = blockIdx.x * 128;
  int tid = threadIdx.x;
  int l = tid & 63, w = tid >> 6;
  int wr = w >> 1, wc = w & 1;
  int lr = l & 15, lg = l >> 4;
  f32x4 acc[4][4] = {};
  int s0 = tid, s1 = tid + 256;  // each thread stages 2x16B per tile per matrix
  int c0 = s0 >> 7, r0 = s0 & 127;
  int c1 = s1 >> 7, r1 = s1 & 127;

  for (int kb = 0; kb < K; kb += 32) {
    __syncthreads();
    gload16(A + (size_t)(mb + r0) * K + kb + c0 * 8, &la[c0][r0][0]);
    gload16(A + (size_t)(mb + r1) * K + kb + c1 * 8, &la[c1][r1][0]);
    gload16(Bt + (size_t)(nb + r0) * K + kb + c0 * 8, &lb[c0][r0][0]);
    gload16(Bt + (size_t)(nb + r1) * K + kb + c1 * 8, &lb[c1][r1][0]);
    __syncthreads();
    bf16x8 af[4], bfr[4];
#pragma unroll
    for (int mi = 0; mi < 4; mi++) af[mi] = ldfrag(&la[lg][wr * 64 + mi * 16 + lr][0]);
#pragma unroll
    for (int ni = 0; ni < 4; ni++) bfr[ni] = ldfrag(&lb[lg][wc * 64 + ni * 16 + lr][0]);
#pragma unroll
    for (int mi = 0; mi < 4; mi++)
#pragma unroll
      for (int ni = 0; ni < 4; ni++)
        acc[mi][ni] = __builtin_amdgcn_mfma_f32_16x16x32_bf16(af[mi], bfr[ni], acc[mi][ni], 0, 0, 0);
  }

#pragma unroll
  for (int mi = 0; mi < 4; mi++) {
#pragma unroll
    for (int ni = 0; ni < 4; ni++) {
      int row0 = mb + wr * 64 + mi * 16 + lg * 4;  // global M row (b*T + t), 4 consecutive
      int col = nb + wc * 64 + ni * 16 + lr;       // global N col
      if (EPI == 1) {
#pragma unroll
        for (int r = 0; r < 4; r++)
          outF[(size_t)(row0 + r) * N + col] = acc[mi][ni][r];
      } else {
        int which = col >> 10, cc = col & 1023;
        int h = cc >> 6, d = cc & 63;
        int bb = row0 >> 11, t = row0 & 2047;
        size_t bh = (size_t)bb * Hv + h;
        if (which == 0) {
#pragma unroll
          for (int r = 0; r < 4; r++)
            qo[(bh * Tv + t + r) * Dv + d] = f2bf(acc[mi][ni][r]);
        } else if (which == 1) {
#pragma unroll
          for (int r = 0; r < 4; r++)
            ko[(bh * Tv + t + r) * Dv + d] = f2bf(acc[mi][ni][r]);
        } else {  // v stored transposed [B,H,D,T]; 4 consecutive t pack to 8B
          ushort4v pk;
#pragma unroll
          for (int r = 0; r < 4; r++) pk[r] = f2bf(acc[mi][ni][r]);
          *reinterpret_cast<ushort4v*>(&vTo[(bh * Dv + d) * Tv + t]) = pk;
        }
      }
    }
  }
}

// ---------------- flash attention ----------------
// grid (qtile=32, bh=32), 256 threads = 4 waves; each wave owns 16 q-rows.
// KT=32 keys per iter; K tile LDS [d-chunk 8][key 32][8], V^T tile [key-chunk 4][d 64][8]
// (both: linear global_load_lds dest + conflict-free b128 reads).
// P goes C-layout -> LDS [16][40] (padded) -> A-layout for PV.
__global__ void __launch_bounds__(256) flash_attn(
    const unsigned short* __restrict__ Q, const unsigned short* __restrict__ Kk,
    const unsigned short* __restrict__ Vt, unsigned short* __restrict__ O) {
  __shared__ unsigned short lK[8][32][8];   // 4KB
  __shared__ unsigned short lV[4][64][8];   // 4KB
  __shared__ unsigned short lP[4][16][40];  // 5KB, wave-private slabs
  const float LOG2E = 1.4426950408889634f;
  int qt = blockIdx.x, bh = blockIdx.y;
  int b = bh >> 4, h = bh & 15;
  int tid = threadIdx.x;
  int l = tid & 63, w = tid >> 6;
  int lr = l & 15, lg = l >> 4;
  const unsigned short* Qp = Q + (size_t)bh * Tv * Dv;
  const unsigned short* Kp = Kk + (size_t)bh * Tv * Dv;
  const unsigned short* Vp = Vt + (size_t)bh * Dv * Tv;
  int q0 = qt * 64;
  int qrow = q0 + w * 16 + lr;  // A-frag m index
  bf16x8 qf0 = ldfrag(&Qp[(size_t)qrow * Dv + lg * 8]);
  bf16x8 qf1 = ldfrag(&Qp[(size_t)qrow * Dv + 32 + lg * 8]);
  f32x4 o0 = {0.f, 0.f, 0.f, 0.f}, o1 = o0, o2 = o0, o3 = o0;
  float mrow[4], lsum[4];
#pragma unroll
  for (int r = 0; r < 4; r++) { mrow[r] = -1e30f; lsum[r] = 0.f; }
  int nt = qt * 2 + 2;  // causal: tiles with k0 <= q0+63
  for (int it = 0; it < nt; ++it) {
    int k0 = it * 32;
    __syncthreads();
    gload16(Kp + (size_t)(k0 + (tid & 31)) * Dv + (tid >> 5) * 8, &lK[tid >> 5][tid & 31][0]);
    gload16(Vp + (size_t)(tid & 63) * Tv + k0 + (tid >> 6) * 8, &lV[tid >> 6][tid & 63][0]);
    __syncthreads();
    // S = Q K^T  (two 16-key column blocks)
    f32x4 sa = {0.f, 0.f, 0.f, 0.f}, sb = sa;
    {
      bf16x8 k00 = ldfrag(&lK[lg][lr][0]);
      bf16x8 k01 = ldfrag(&lK[4 + lg][lr][0]);
      sa = __builtin_amdgcn_mfma_f32_16x16x32_bf16(qf0, k00, sa, 0, 0, 0);
      sa = __builtin_amdgcn_mfma_f32_16x16x32_bf16(qf1, k01, sa, 0, 0, 0);
      bf16x8 k10 = ldfrag(&lK[lg][16 + lr][0]);
      bf16x8 k11 = ldfrag(&lK[4 + lg][16 + lr][0]);
      sb = __builtin_amdgcn_mfma_f32_16x16x32_bf16(qf0, k10, sb, 0, 0, 0);
      sb = __builtin_amdgcn_mfma_f32_16x16x32_bf16(qf1, k11, sb, 0, 0, 0);
    }
    // scale + causal mask (C layout: row = lg*4+r, col = lr)
    int qg0 = q0 + w * 16 + lg * 4;
#pragma unroll
    for (int r = 0; r < 4; r++) {
      int qg = qg0 + r;
      sa[r] = (k0 + lr <= qg) ? sa[r] * 0.125f : -1e30f;
      sb[r] = (k0 + 16 + lr <= qg) ? sb[r] * 0.125f : -1e30f;
    }
    // online softmax
    float al[4];
#pragma unroll
    for (int r = 0; r < 4; r++) {
      float v = fmaxf(sa[r], sb[r]);
      v = fmaxf(v, __shfl_xor(v, 1));
      v = fmaxf(v, __shfl_xor(v, 2));
      v = fmaxf(v, __shfl_xor(v, 4));
      v = fmaxf(v, __shfl_xor(v, 8));
      float mn = fmaxf(mrow[r], v);
      al[r] = exp2f((mrow[r] - mn) * LOG2E);
      mrow[r] = mn;
    }
#pragma unroll
    for (int r = 0; r < 4; r++) {
      float p0 = exp2f((sa[r] - mrow[r]) * LOG2E);
      float p1 = exp2f((sb[r] - mrow[r]) * LOG2E);
      float v = p0 + p1;
      v += __shfl_xor(v, 1);
      v += __shfl_xor(v, 2);
      v += __shfl_xor(v, 4);
      v += __shfl_xor(v, 8);
      lsum[r] = lsum[r] * al[r] + v;
      o0[r] *= al[r]; o1[r] *= al[r]; o2[r] *= al[r]; o3[r] *= al[r];
      lP[w][lg * 4 + r][lr] = f2bf(p0);
      lP[w][lg * 4 + r][16 + lr] = f2bf(p1);
    }
    // PV: A = P (from wave-private LDS), B = V^T tile
    bf16x8 pf = ldfrag(&lP[w][lr][lg * 8]);
    bf16x8 v0 = ldfrag(&lV[lg][lr][0]);
    o0 = __builtin_amdgcn_mfma_f32_16x16x32_bf16(pf, v0, o0, 0, 0, 0);
    bf16x8 v1 = ldfrag(&lV[lg][16 + lr][0]);
    o1 = __builtin_amdgcn_mfma_f32_16x16x32_bf16(pf, v1, o1, 0, 0, 0);
    bf16x8 v2 = ldfrag(&lV[lg][32 + lr][0]);
    o2 = __builtin_amdgcn_mfma_f32_16x16x32_bf16(pf, v2, o2, 0, 0, 0);
    bf16x8 v3 = ldfrag(&lV[lg][48 + lr][0]);
    o3 = __builtin_amdgcn_mfma_f32_16x16x32_bf16(pf, v3, o3, 0, 0, 0);
  }
  // epilogue: normalize, write [B,T,H*D] bf16
#pragma unroll
  for (int r = 0; r < 4; r++) {
    int t = q0 + w * 16 + lg * 4 + r;
    float inv = 1.0f / lsum[r];
    size_t rowbase = ((size_t)b * Tv + t) * Cv + h * Dv;
    O[rowbase + lr] = f2bf(o0[r] * inv);
    O[rowbase + 16 + lr] = f2bf(o1[r] * inv);
    O[rowbase + 32 + lr] = f2bf(o2[r] * inv);
    O[rowbase + 48 + lr] = f2bf(o3[r] * inv);
  }
}

// ---------------- host ----------------
extern "C" void kernel_launch(void* const* d_in, const int* in_sizes, int n_in,
                              void* d_out, int out_size, void* d_ws, size_t ws_size,
                              hipStream_t stream) {
  const float* x = (const float*)d_in[0];      // [2,2048,1024]
  const float* w_qkv = (const float*)d_in[1];  // [1024,3072]
  const float* w_out = (const float*)d_in[2];  // [1024,1024]
  float* out = (float*)d_out;                  // [2,2048,1024] f32
  char* ws = (char*)d_ws;
  const size_t MB = 1u << 20;
  unsigned short* xb    = (unsigned short*)(ws + 0);        // 8MB  [4096][1024]
  unsigned short* wqkvT = (unsigned short*)(ws + 8 * MB);   // 6MB  [3072][1024]
  unsigned short* woutT = (unsigned short*)(ws + 14 * MB);  // 2MB  [1024][1024]
  unsigned short* qb    = (unsigned short*)(ws + 16 * MB);  // 8MB  [B,H,T,D]
  unsigned short* kb    = (unsigned short*)(ws + 24 * MB);  // 8MB  [B,H,T,D]
  unsigned short* vTb   = (unsigned short*)(ws + 32 * MB);  // 8MB  [B,H,D,T]
  unsigned short* ab    = (unsigned short*)(ws + 40 * MB);  // 8MB  [4096][1024]

  cast_bf16<<<dim3(Mv * Cv / (256 * 8)), dim3(256), 0, stream>>>(x, xb);
  transcast<<<dim3(3072 / 32, 1024 / 32), dim3(256), 0, stream>>>(w_qkv, wqkvT, 1024, 3072);
  transcast<<<dim3(1024 / 32, 1024 / 32), dim3(256), 0, stream>>>(w_out, woutT, 1024, 1024);
  gemm128<0><<<dim3(3072 / 128, Mv / 128), dim3(256), 0, stream>>>(
      xb, wqkvT, nullptr, qb, kb, vTb, 3072);
  flash_attn<<<dim3(Tv / 64, Bv * Hv), dim3(256), 0, stream>>>(qb, kb, vTb, ab);
  gemm128<1><<<dim3(Cv / 128, Mv / 128), dim3(256), 0, stream>>>(
      ab, woutT, out, nullptr, nullptr, nullptr, Cv);
}

// Round 2
// 221.768 us; speedup vs baseline: 1.2649x; 1.2649x over previous
//
#include <hip/hip_runtime.h>
#include <hip/hip_bf16.h>
#include <stdint.h>

// B=2, T=2048, C=1024, H=16, D=64
// out = ( causal_attn(x@Wqkv) ) @ Wout
// bf16 MFMA pipeline, f32 accumulate everywhere.
// R2: T3 double-buffered staging (one __syncthreads per tile, prefetch in
// flight across compute), flash KT=64, diagonal-only masking.

#define Bv 2
#define Tv 2048
#define Cv 1024
#define Hv 16
#define Dv 64
#define Mv 4096  // B*T

typedef __attribute__((ext_vector_type(8))) __bf16 bf16x8;
typedef __attribute__((ext_vector_type(4))) float f32x4;
typedef __attribute__((ext_vector_type(4))) unsigned short ushort4v;

__device__ __forceinline__ unsigned short f2bf(float f) {
  union { float f; unsigned int u; } v; v.f = f;
  unsigned int r = (v.u + 0x7FFFu + ((v.u >> 16) & 1u)) >> 16;  // RNE
  return (unsigned short)r;
}

__device__ __forceinline__ void gload16(const void* g, void* l) {
  __builtin_amdgcn_global_load_lds(
      (__attribute__((address_space(1))) void*)(uintptr_t)g,
      (__attribute__((address_space(3))) void*)(unsigned int)(uintptr_t)l,
      16, 0, 0);
}

__device__ __forceinline__ bf16x8 ldfrag(const unsigned short* p) {
  return *reinterpret_cast<const bf16x8*>(p);
}

// ---------------- cast f32 -> bf16, 8 elems/thread ----------------
__global__ void __launch_bounds__(256) cast_bf16(const float* __restrict__ in,
                                                 unsigned short* __restrict__ out) {
  int i = (blockIdx.x * 256 + threadIdx.x) * 8;
  float4 a = *reinterpret_cast<const float4*>(in + i);
  float4 b = *reinterpret_cast<const float4*>(in + i + 4);
  ushort4v o0, o1;
  o0.x = f2bf(a.x); o0.y = f2bf(a.y); o0.z = f2bf(a.z); o0.w = f2bf(a.w);
  o1.x = f2bf(b.x); o1.y = f2bf(b.y); o1.z = f2bf(b.z); o1.w = f2bf(b.w);
  *reinterpret_cast<ushort4v*>(out + i) = o0;
  *reinterpret_cast<ushort4v*>(out + i + 4) = o1;
}

// ---------------- transpose + cast: in f32 [R][Cc] -> out bf16 [Cc][R] ----------------
__global__ void __launch_bounds__(256) transcast(const float* __restrict__ in,
                                                 unsigned short* __restrict__ out,
                                                 int R, int Cc) {
  __shared__ float tile[32][33];
  int c0 = blockIdx.x * 32;
  int r0 = blockIdx.y * 32;
  int tc = threadIdx.x & 31, tr = threadIdx.x >> 5;
#pragma unroll
  for (int i = 0; i < 4; i++)
    tile[tr + i * 8][tc] = in[(size_t)(r0 + tr + i * 8) * Cc + c0 + tc];
  __syncthreads();
#pragma unroll
  for (int i = 0; i < 4; i++)
    out[(size_t)(c0 + tr + i * 8) * R + r0 + tc] = f2bf(tile[tc][tr + i * 8]);
}

// ---------------- GEMM: C[M][N] = A[M][1024] * Bt[N][1024]^T ----------------
// 128x128 tile, BK=32, 256 threads (2x2 waves, each 64x64 = 4x4 MFMA frags).
// Double-buffered LDS, ONE __syncthreads per K-step; prefetch of step k+1
// overlaps MFMA of step k (drained by the next barrier's vmcnt(0)).
template <int EPI>
__global__ void __launch_bounds__(256) gemm128(
    const unsigned short* __restrict__ A, const unsigned short* __restrict__ Bt,
    float* __restrict__ outF, unsigned short* __restrict__ qo,
    unsigned short* __restrict__ ko, unsigned short* __restrict__ vTo, int N) {
  __shared__ unsigned short la[2][4][128][8];
  __shared__ unsigned short lb[2][4][128][8];
  const int K = 1024;
  int mb = blockIdx.y * 128, nb = blockIdx.x * 128;
  int tid = threadIdx.x;
  int l = tid & 63, w = tid >> 6;
  int wr = w >> 1, wc = w & 1;
  int lr = l & 15, lg = l >> 4;
  f32x4 acc[4][4] = {};
  int c0 = tid >> 7, r0 = tid & 127;  // each thread stages 2x16B per matrix

  auto STAGE = [&](int kb, int buf) {
    gload16(A + (size_t)(mb + r0) * K + kb + c0 * 8, &la[buf][c0][r0][0]);
    gload16(A + (size_t)(mb + r0) * K + kb + (c0 + 2) * 8, &la[buf][c0 + 2][r0][0]);
    gload16(Bt + (size_t)(nb + r0) * K + kb + c0 * 8, &lb[buf][c0][r0][0]);
    gload16(Bt + (size_t)(nb + r0) * K + kb + (c0 + 2) * 8, &lb[buf][c0 + 2][r0][0]);
  };

  STAGE(0, 0);
  int cur = 0;
  for (int kb = 0; kb < K; kb += 32) {
    __syncthreads();  // drains prev prefetch (vmcnt(0)) + protects buffer reuse
    if (kb + 32 < K) STAGE(kb + 32, cur ^ 1);
    bf16x8 af[4], bfr[4];
#pragma unroll
    for (int mi = 0; mi < 4; mi++) af[mi] = ldfrag(&la[cur][lg][wr * 64 + mi * 16 + lr][0]);
#pragma unroll
    for (int ni = 0; ni < 4; ni++) bfr[ni] = ldfrag(&lb[cur][lg][wc * 64 + ni * 16 + lr][0]);
#pragma unroll
    for (int mi = 0; mi < 4; mi++)
#pragma unroll
      for (int ni = 0; ni < 4; ni++)
        acc[mi][ni] = __builtin_amdgcn_mfma_f32_16x16x32_bf16(af[mi], bfr[ni], acc[mi][ni], 0, 0, 0);
    cur ^= 1;
  }

#pragma unroll
  for (int mi = 0; mi < 4; mi++) {
#pragma unroll
    for (int ni = 0; ni < 4; ni++) {
      int row0 = mb + wr * 64 + mi * 16 + lg * 4;  // global M row, 4 consecutive
      int col = nb + wc * 64 + ni * 16 + lr;       // global N col
      if (EPI == 1) {
#pragma unroll
        for (int r = 0; r < 4; r++)
          outF[(size_t)(row0 + r) * N + col] = acc[mi][ni][r];
      } else {
        int which = col >> 10, cc = col & 1023;
        int h = cc >> 6, d = cc & 63;
        int bb = row0 >> 11, t = row0 & 2047;
        size_t bh = (size_t)bb * Hv + h;
        if (which == 0) {
#pragma unroll
          for (int r = 0; r < 4; r++)
            qo[(bh * Tv + t + r) * Dv + d] = f2bf(acc[mi][ni][r]);
        } else if (which == 1) {
#pragma unroll
          for (int r = 0; r < 4; r++)
            ko[(bh * Tv + t + r) * Dv + d] = f2bf(acc[mi][ni][r]);
        } else {  // v stored transposed [B,H,D,T]
          ushort4v pk;
#pragma unroll
          for (int r = 0; r < 4; r++) pk[r] = f2bf(acc[mi][ni][r]);
          *reinterpret_cast<ushort4v*>(&vTo[(bh * Dv + d) * Tv + t]) = pk;
        }
      }
    }
  }
}

// ---------------- flash attention ----------------
// grid (qtile=32, bh=32), 256 threads = 4 waves; each wave owns 16 q-rows.
// KT=64 keys per iter, double-buffered K and V, one __syncthreads per tile.
// Mask only the diagonal tile (it == nt-1), uniform branch.
__global__ void __launch_bounds__(256) flash_attn(
    const unsigned short* __restrict__ Q, const unsigned short* __restrict__ Kk,
    const unsigned short* __restrict__ Vt, unsigned short* __restrict__ O) {
  __shared__ unsigned short lK[2][8][64][8];  // 16KB
  __shared__ unsigned short lV[2][8][64][8];  // 16KB
  __shared__ unsigned short lP[4][16][72];    // 9KB, wave-private slabs
  int qt = blockIdx.x, bh = blockIdx.y;
  int b = bh >> 4, h = bh & 15;
  int tid = threadIdx.x;
  int l = tid & 63, w = tid >> 6;
  int lr = l & 15, lg = l >> 4;
  const unsigned short* Qp = Q + (size_t)bh * Tv * Dv;
  const unsigned short* Kp = Kk + (size_t)bh * Tv * Dv;
  const unsigned short* Vp = Vt + (size_t)bh * Dv * Tv;
  int q0 = qt * 64;
  int qrow = q0 + w * 16 + lr;
  bf16x8 qf0 = ldfrag(&Qp[(size_t)qrow * Dv + lg * 8]);
  bf16x8 qf1 = ldfrag(&Qp[(size_t)qrow * Dv + 32 + lg * 8]);
  f32x4 o[4] = {};
  float mrow[4], lsum[4];
#pragma unroll
  for (int r = 0; r < 4; r++) { mrow[r] = -1e30f; lsum[r] = 0.f; }
  const float Cs = 0.125f * 1.4426950408889634f;  // scale * log2(e)
  int nt = qt + 1;
  int sr = tid & 63, sc = tid >> 6;  // staging: row, chunk-base

  auto STAGE = [&](int it, int buf) {
    int k0 = it * 64;
    gload16(Kp + (size_t)(k0 + sr) * Dv + sc * 8, &lK[buf][sc][sr][0]);
    gload16(Kp + (size_t)(k0 + sr) * Dv + (sc + 4) * 8, &lK[buf][sc + 4][sr][0]);
    gload16(Vp + (size_t)sr * Tv + k0 + sc * 8, &lV[buf][sc][sr][0]);
    gload16(Vp + (size_t)sr * Tv + k0 + (sc + 4) * 8, &lV[buf][sc + 4][sr][0]);
  };

  STAGE(0, 0);
  int cur = 0;
  for (int it = 0; it < nt; ++it) {
    __syncthreads();  // drains prefetch of tile `it` + protects buffer reuse
    if (it + 1 < nt) STAGE(it + 1, cur ^ 1);
    int k0 = it * 64;
    // S = Q K^T : 4 column blocks of 16 keys, C-layout (row = lg*4+r, col = lr)
    f32x4 s[4] = {};
#pragma unroll
    for (int j = 0; j < 4; ++j) {
      bf16x8 kf0 = ldfrag(&lK[cur][lg][j * 16 + lr][0]);
      s[j] = __builtin_amdgcn_mfma_f32_16x16x32_bf16(qf0, kf0, s[j], 0, 0, 0);
      bf16x8 kf1 = ldfrag(&lK[cur][4 + lg][j * 16 + lr][0]);
      s[j] = __builtin_amdgcn_mfma_f32_16x16x32_bf16(qf1, kf1, s[j], 0, 0, 0);
    }
    int qg0 = q0 + w * 16 + lg * 4;
    if (it == nt - 1) {  // diagonal tile only
#pragma unroll
      for (int j = 0; j < 4; ++j)
#pragma unroll
        for (int r = 0; r < 4; ++r)
          if (k0 + j * 16 + lr > qg0 + r) s[j][r] = -1e30f;
    }
    // online softmax (raw-S domain, scale folded into exp2 arg)
    float al[4];
#pragma unroll
    for (int r = 0; r < 4; ++r) {
      float v = fmaxf(fmaxf(s[0][r], s[1][r]), fmaxf(s[2][r], s[3][r]));
      v = fmaxf(v, __shfl_xor(v, 1));
      v = fmaxf(v, __shfl_xor(v, 2));
      v = fmaxf(v, __shfl_xor(v, 4));
      v = fmaxf(v, __shfl_xor(v, 8));
      float mn = fmaxf(mrow[r], v);
      al[r] = exp2f((mrow[r] - mn) * Cs);
      mrow[r] = mn;
    }
#pragma unroll
    for (int r = 0; r < 4; ++r) {
      float p0 = exp2f((s[0][r] - mrow[r]) * Cs);
      float p1 = exp2f((s[1][r] - mrow[r]) * Cs);
      float p2 = exp2f((s[2][r] - mrow[r]) * Cs);
      float p3 = exp2f((s[3][r] - mrow[r]) * Cs);
      float sm = (p0 + p1) + (p2 + p3);
      sm += __shfl_xor(sm, 1);
      sm += __shfl_xor(sm, 2);
      sm += __shfl_xor(sm, 4);
      sm += __shfl_xor(sm, 8);
      lsum[r] = lsum[r] * al[r] + sm;
#pragma unroll
      for (int nb = 0; nb < 4; ++nb) o[nb][r] *= al[r];
      lP[w][lg * 4 + r][lr] = f2bf(p0);
      lP[w][lg * 4 + r][16 + lr] = f2bf(p1);
      lP[w][lg * 4 + r][32 + lr] = f2bf(p2);
      lP[w][lg * 4 + r][48 + lr] = f2bf(p3);
    }
    // PV: A = P (wave-private LDS), B = V^T tile; 2 k-steps of 32 keys
#pragma unroll
    for (int kk = 0; kk < 2; ++kk) {
      bf16x8 pf = ldfrag(&lP[w][lr][kk * 32 + lg * 8]);
#pragma unroll
      for (int nb = 0; nb < 4; ++nb) {
        bf16x8 vf = ldfrag(&lV[cur][kk * 4 + lg][nb * 16 + lr][0]);
        o[nb] = __builtin_amdgcn_mfma_f32_16x16x32_bf16(pf, vf, o[nb], 0, 0, 0);
      }
    }
    cur ^= 1;
  }
  // epilogue: normalize, write [B,T,H*D] bf16
#pragma unroll
  for (int r = 0; r < 4; ++r) {
    int t = q0 + w * 16 + lg * 4 + r;
    float inv = 1.0f / lsum[r];
    size_t rowbase = ((size_t)b * Tv + t) * Cv + h * Dv;
#pragma unroll
    for (int nb = 0; nb < 4; ++nb)
      O[rowbase + nb * 16 + lr] = f2bf(o[nb][r] * inv);
  }
}

// ---------------- host ----------------
extern "C" void kernel_launch(void* const* d_in, const int* in_sizes, int n_in,
                              void* d_out, int out_size, void* d_ws, size_t ws_size,
                              hipStream_t stream) {
  const float* x = (const float*)d_in[0];      // [2,2048,1024]
  const float* w_qkv = (const float*)d_in[1];  // [1024,3072]
  const float* w_out = (const float*)d_in[2];  // [1024,1024]
  float* out = (float*)d_out;                  // [2,2048,1024] f32
  char* ws = (char*)d_ws;
  const size_t MB = 1u << 20;
  unsigned short* xb    = (unsigned short*)(ws + 0);        // 8MB  [4096][1024]
  unsigned short* wqkvT = (unsigned short*)(ws + 8 * MB);   // 6MB  [3072][1024]
  unsigned short* woutT = (unsigned short*)(ws + 14 * MB);  // 2MB  [1024][1024]
  unsigned short* qb    = (unsigned short*)(ws + 16 * MB);  // 8MB  [B,H,T,D]
  unsigned short* kb    = (unsigned short*)(ws + 24 * MB);  // 8MB  [B,H,T,D]
  unsigned short* vTb   = (unsigned short*)(ws + 32 * MB);  // 8MB  [B,H,D,T]
  unsigned short* ab    = (unsigned short*)(ws + 40 * MB);  // 8MB  [4096][1024]

  cast_bf16<<<dim3(Mv * Cv / (256 * 8)), dim3(256), 0, stream>>>(x, xb);
  transcast<<<dim3(3072 / 32, 1024 / 32), dim3(256), 0, stream>>>(w_qkv, wqkvT, 1024, 3072);
  transcast<<<dim3(1024 / 32, 1024 / 32), dim3(256), 0, stream>>>(w_out, woutT, 1024, 1024);
  gemm128<0><<<dim3(3072 / 128, Mv / 128), dim3(256), 0, stream>>>(
      xb, wqkvT, nullptr, qb, kb, vTb, 3072);
  flash_attn<<<dim3(Tv / 64, Bv * Hv), dim3(256), 0, stream>>>(qb, kb, vTb, ab);
  gemm128<1><<<dim3(Cv / 128, Mv / 128), dim3(256), 0, stream>>>(
      ab, woutT, out, nullptr, nullptr, nullptr, Cv);
}

// Round 3
// 161.938 us; speedup vs baseline: 1.7323x; 1.3695x over previous
//
#include <hip/hip_runtime.h>
#include <hip/hip_bf16.h>
#include <stdint.h>

// B=2, T=2048, C=1024, H=16, D=64
// out = ( causal_attn(x@Wqkv) ) @ Wout
// bf16 MFMA pipeline, f32 accumulate everywhere.
// R3: flash load-balance via q-tile pairing (i, 31-i) -> uniform 33 tiles/blk,
// grid 512 = 2 blocks/CU; softmax row-sum via MFMA ones-trick (kills the
// 16-shuffle sum chain). GEMMs unchanged from R2.

#define Bv 2
#define Tv 2048
#define Cv 1024
#define Hv 16
#define Dv 64
#define Mv 4096  // B*T

typedef __attribute__((ext_vector_type(8))) __bf16 bf16x8;
typedef __attribute__((ext_vector_type(4))) float f32x4;
typedef __attribute__((ext_vector_type(4))) unsigned short ushort4v;

__device__ __forceinline__ unsigned short f2bf(float f) {
  union { float f; unsigned int u; } v; v.f = f;
  unsigned int r = (v.u + 0x7FFFu + ((v.u >> 16) & 1u)) >> 16;  // RNE
  return (unsigned short)r;
}

__device__ __forceinline__ void gload16(const void* g, void* l) {
  __builtin_amdgcn_global_load_lds(
      (__attribute__((address_space(1))) void*)(uintptr_t)g,
      (__attribute__((address_space(3))) void*)(unsigned int)(uintptr_t)l,
      16, 0, 0);
}

__device__ __forceinline__ bf16x8 ldfrag(const unsigned short* p) {
  return *reinterpret_cast<const bf16x8*>(p);
}

// ---------------- cast f32 -> bf16, 8 elems/thread ----------------
__global__ void __launch_bounds__(256) cast_bf16(const float* __restrict__ in,
                                                 unsigned short* __restrict__ out) {
  int i = (blockIdx.x * 256 + threadIdx.x) * 8;
  float4 a = *reinterpret_cast<const float4*>(in + i);
  float4 b = *reinterpret_cast<const float4*>(in + i + 4);
  ushort4v o0, o1;
  o0.x = f2bf(a.x); o0.y = f2bf(a.y); o0.z = f2bf(a.z); o0.w = f2bf(a.w);
  o1.x = f2bf(b.x); o1.y = f2bf(b.y); o1.z = f2bf(b.z); o1.w = f2bf(b.w);
  *reinterpret_cast<ushort4v*>(out + i) = o0;
  *reinterpret_cast<ushort4v*>(out + i + 4) = o1;
}

// ---------------- transpose + cast: in f32 [R][Cc] -> out bf16 [Cc][R] ----------------
__global__ void __launch_bounds__(256) transcast(const float* __restrict__ in,
                                                 unsigned short* __restrict__ out,
                                                 int R, int Cc) {
  __shared__ float tile[32][33];
  int c0 = blockIdx.x * 32;
  int r0 = blockIdx.y * 32;
  int tc = threadIdx.x & 31, tr = threadIdx.x >> 5;
#pragma unroll
  for (int i = 0; i < 4; i++)
    tile[tr + i * 8][tc] = in[(size_t)(r0 + tr + i * 8) * Cc + c0 + tc];
  __syncthreads();
#pragma unroll
  for (int i = 0; i < 4; i++)
    out[(size_t)(c0 + tr + i * 8) * R + r0 + tc] = f2bf(tile[tc][tr + i * 8]);
}

// ---------------- GEMM: C[M][N] = A[M][1024] * Bt[N][1024]^T ----------------
// 128x128 tile, BK=32, 256 threads (2x2 waves, each 64x64 = 4x4 MFMA frags).
// Double-buffered LDS, ONE __syncthreads per K-step.
template <int EPI>
__global__ void __launch_bounds__(256) gemm128(
    const unsigned short* __restrict__ A, const unsigned short* __restrict__ Bt,
    float* __restrict__ outF, unsigned short* __restrict__ qo,
    unsigned short* __restrict__ ko, unsigned short* __restrict__ vTo, int N) {
  __shared__ unsigned short la[2][4][128][8];
  __shared__ unsigned short lb[2][4][128][8];
  const int K = 1024;
  int mb = blockIdx.y * 128, nb = blockIdx.x * 128;
  int tid = threadIdx.x;
  int l = tid & 63, w = tid >> 6;
  int wr = w >> 1, wc = w & 1;
  int lr = l & 15, lg = l >> 4;
  f32x4 acc[4][4] = {};
  int c0 = tid >> 7, r0 = tid & 127;

  auto STAGE = [&](int kb, int buf) {
    gload16(A + (size_t)(mb + r0) * K + kb + c0 * 8, &la[buf][c0][r0][0]);
    gload16(A + (size_t)(mb + r0) * K + kb + (c0 + 2) * 8, &la[buf][c0 + 2][r0][0]);
    gload16(Bt + (size_t)(nb + r0) * K + kb + c0 * 8, &lb[buf][c0][r0][0]);
    gload16(Bt + (size_t)(nb + r0) * K + kb + (c0 + 2) * 8, &lb[buf][c0 + 2][r0][0]);
  };

  STAGE(0, 0);
  int cur = 0;
  for (int kb = 0; kb < K; kb += 32) {
    __syncthreads();
    if (kb + 32 < K) STAGE(kb + 32, cur ^ 1);
    bf16x8 af[4], bfr[4];
#pragma unroll
    for (int mi = 0; mi < 4; mi++) af[mi] = ldfrag(&la[cur][lg][wr * 64 + mi * 16 + lr][0]);
#pragma unroll
    for (int ni = 0; ni < 4; ni++) bfr[ni] = ldfrag(&lb[cur][lg][wc * 64 + ni * 16 + lr][0]);
#pragma unroll
    for (int mi = 0; mi < 4; mi++)
#pragma unroll
      for (int ni = 0; ni < 4; ni++)
        acc[mi][ni] = __builtin_amdgcn_mfma_f32_16x16x32_bf16(af[mi], bfr[ni], acc[mi][ni], 0, 0, 0);
    cur ^= 1;
  }

#pragma unroll
  for (int mi = 0; mi < 4; mi++) {
#pragma unroll
    for (int ni = 0; ni < 4; ni++) {
      int row0 = mb + wr * 64 + mi * 16 + lg * 4;
      int col = nb + wc * 64 + ni * 16 + lr;
      if (EPI == 1) {
#pragma unroll
        for (int r = 0; r < 4; r++)
          outF[(size_t)(row0 + r) * N + col] = acc[mi][ni][r];
      } else {
        int which = col >> 10, cc = col & 1023;
        int h = cc >> 6, d = cc & 63;
        int bb = row0 >> 11, t = row0 & 2047;
        size_t bh = (size_t)bb * Hv + h;
        if (which == 0) {
#pragma unroll
          for (int r = 0; r < 4; r++)
            qo[(bh * Tv + t + r) * Dv + d] = f2bf(acc[mi][ni][r]);
        } else if (which == 1) {
#pragma unroll
          for (int r = 0; r < 4; r++)
            ko[(bh * Tv + t + r) * Dv + d] = f2bf(acc[mi][ni][r]);
        } else {  // v stored transposed [B,H,D,T]
          ushort4v pk;
#pragma unroll
          for (int r = 0; r < 4; r++) pk[r] = f2bf(acc[mi][ni][r]);
          *reinterpret_cast<ushort4v*>(&vTo[(bh * Dv + d) * Tv + t]) = pk;
        }
      }
    }
  }
}

// ---------------- flash attention ----------------
// grid (pair=16, bh=32), 256 threads = 4 waves; each wave owns 16 q-rows.
// Each block processes q-tiles {i, 31-i} sequentially -> uniform 33 K-tiles.
// KT=64, double-buffered K/V, one __syncthreads per tile.
// Row-sum via MFMA ones-trick; row-max via 4x shfl_xor.
__global__ void __launch_bounds__(256) flash_attn(
    const unsigned short* __restrict__ Q, const unsigned short* __restrict__ Kk,
    const unsigned short* __restrict__ Vt, unsigned short* __restrict__ O) {
  __shared__ unsigned short lK[2][8][64][8];  // 16KB
  __shared__ unsigned short lV[2][8][64][8];  // 16KB
  __shared__ unsigned short lP[4][16][72];    // 9KB, wave-private slabs
  int bh = blockIdx.y;
  int b = bh >> 4, h = bh & 15;
  int tid = threadIdx.x;
  int l = tid & 63, w = tid >> 6;
  int lr = l & 15, lg = l >> 4;
  const unsigned short* Qp = Q + (size_t)bh * Tv * Dv;
  const unsigned short* Kp = Kk + (size_t)bh * Tv * Dv;
  const unsigned short* Vp = Vt + (size_t)bh * Dv * Tv;
  const float Cs = 0.125f * 1.4426950408889634f;  // scale * log2(e)
  const __bf16 kOne = (__bf16)1.0f;
  const bf16x8 vone = {kOne, kOne, kOne, kOne, kOne, kOne, kOne, kOne};
  int sr = tid & 63, sc = tid >> 6;  // staging: row, chunk-base

  for (int ph = 0; ph < 2; ++ph) {
    int qt = ph ? (31 - (int)blockIdx.x) : (int)blockIdx.x;
    int q0 = qt * 64;
    int nt = qt + 1;
    int qrow = q0 + w * 16 + lr;
    bf16x8 qf0 = ldfrag(&Qp[(size_t)qrow * Dv + lg * 8]);
    bf16x8 qf1 = ldfrag(&Qp[(size_t)qrow * Dv + 32 + lg * 8]);
    f32x4 o[4] = {};
    float mrow[4], lsum[4];
#pragma unroll
    for (int r = 0; r < 4; r++) { mrow[r] = -1e30f; lsum[r] = 0.f; }

    auto STAGE = [&](int it, int buf) {
      int k0 = it * 64;
      gload16(Kp + (size_t)(k0 + sr) * Dv + sc * 8, &lK[buf][sc][sr][0]);
      gload16(Kp + (size_t)(k0 + sr) * Dv + (sc + 4) * 8, &lK[buf][sc + 4][sr][0]);
      gload16(Vp + (size_t)sr * Tv + k0 + sc * 8, &lV[buf][sc][sr][0]);
      gload16(Vp + (size_t)sr * Tv + k0 + (sc + 4) * 8, &lV[buf][sc + 4][sr][0]);
    };

    if (ph) __syncthreads();  // protect LDS reuse across the phase boundary
    STAGE(0, 0);
    int cur = 0;
    for (int it = 0; it < nt; ++it) {
      __syncthreads();  // drains prefetch of tile `it` + protects buffer reuse
      if (it + 1 < nt) STAGE(it + 1, cur ^ 1);
      int k0 = it * 64;
      // S = Q K^T : 4 column blocks of 16 keys, C-layout (row = lg*4+r, col = lr)
      f32x4 s[4] = {};
#pragma unroll
      for (int j = 0; j < 4; ++j) {
        bf16x8 kf0 = ldfrag(&lK[cur][lg][j * 16 + lr][0]);
        s[j] = __builtin_amdgcn_mfma_f32_16x16x32_bf16(qf0, kf0, s[j], 0, 0, 0);
        bf16x8 kf1 = ldfrag(&lK[cur][4 + lg][j * 16 + lr][0]);
        s[j] = __builtin_amdgcn_mfma_f32_16x16x32_bf16(qf1, kf1, s[j], 0, 0, 0);
      }
      int qg0 = q0 + w * 16 + lg * 4;
      if (it == nt - 1) {  // diagonal tile only
#pragma unroll
        for (int j = 0; j < 4; ++j)
#pragma unroll
          for (int r = 0; r < 4; ++r)
            if (k0 + j * 16 + lr > qg0 + r) s[j][r] = -1e30f;
      }
      // online softmax: row-max via shuffles, row-sum via MFMA below
      float al[4];
#pragma unroll
      for (int r = 0; r < 4; ++r) {
        float v = fmaxf(fmaxf(s[0][r], s[1][r]), fmaxf(s[2][r], s[3][r]));
        v = fmaxf(v, __shfl_xor(v, 1));
        v = fmaxf(v, __shfl_xor(v, 2));
        v = fmaxf(v, __shfl_xor(v, 4));
        v = fmaxf(v, __shfl_xor(v, 8));
        float mn = fmaxf(mrow[r], v);
        al[r] = exp2f((mrow[r] - mn) * Cs);
        mrow[r] = mn;
      }
#pragma unroll
      for (int r = 0; r < 4; ++r) {
        float p0 = exp2f((s[0][r] - mrow[r]) * Cs);
        float p1 = exp2f((s[1][r] - mrow[r]) * Cs);
        float p2 = exp2f((s[2][r] - mrow[r]) * Cs);
        float p3 = exp2f((s[3][r] - mrow[r]) * Cs);
        lsum[r] *= al[r];
#pragma unroll
        for (int nb = 0; nb < 4; ++nb) o[nb][r] *= al[r];
        lP[w][lg * 4 + r][lr] = f2bf(p0);
        lP[w][lg * 4 + r][16 + lr] = f2bf(p1);
        lP[w][lg * 4 + r][32 + lr] = f2bf(p2);
        lP[w][lg * 4 + r][48 + lr] = f2bf(p3);
      }
      // PV + row-sum: A = P (wave-private LDS), B = V^T tile / ones
      f32x4 srow = {0.f, 0.f, 0.f, 0.f};
#pragma unroll
      for (int kk = 0; kk < 2; ++kk) {
        bf16x8 pf = ldfrag(&lP[w][lr][kk * 32 + lg * 8]);
        srow = __builtin_amdgcn_mfma_f32_16x16x32_bf16(pf, vone, srow, 0, 0, 0);
#pragma unroll
        for (int nb = 0; nb < 4; ++nb) {
          bf16x8 vf = ldfrag(&lV[cur][kk * 4 + lg][nb * 16 + lr][0]);
          o[nb] = __builtin_amdgcn_mfma_f32_16x16x32_bf16(pf, vf, o[nb], 0, 0, 0);
        }
      }
#pragma unroll
      for (int r = 0; r < 4; ++r) lsum[r] += srow[r];
      cur ^= 1;
    }
    // epilogue: normalize, write [B,T,H*D] bf16
#pragma unroll
    for (int r = 0; r < 4; ++r) {
      int t = q0 + w * 16 + lg * 4 + r;
      float inv = 1.0f / lsum[r];
      size_t rowbase = ((size_t)b * Tv + t) * Cv + h * Dv;
#pragma unroll
      for (int nb = 0; nb < 4; ++nb)
        O[rowbase + nb * 16 + lr] = f2bf(o[nb][r] * inv);
    }
  }
}

// ---------------- host ----------------
extern "C" void kernel_launch(void* const* d_in, const int* in_sizes, int n_in,
                              void* d_out, int out_size, void* d_ws, size_t ws_size,
                              hipStream_t stream) {
  const float* x = (const float*)d_in[0];      // [2,2048,1024]
  const float* w_qkv = (const float*)d_in[1];  // [1024,3072]
  const float* w_out = (const float*)d_in[2];  // [1024,1024]
  float* out = (float*)d_out;                  // [2,2048,1024] f32
  char* ws = (char*)d_ws;
  const size_t MB = 1u << 20;
  unsigned short* xb    = (unsigned short*)(ws + 0);        // 8MB  [4096][1024]
  unsigned short* wqkvT = (unsigned short*)(ws + 8 * MB);   // 6MB  [3072][1024]
  unsigned short* woutT = (unsigned short*)(ws + 14 * MB);  // 2MB  [1024][1024]
  unsigned short* qb    = (unsigned short*)(ws + 16 * MB);  // 8MB  [B,H,T,D]
  unsigned short* kb    = (unsigned short*)(ws + 24 * MB);  // 8MB  [B,H,T,D]
  unsigned short* vTb   = (unsigned short*)(ws + 32 * MB);  // 8MB  [B,H,D,T]
  unsigned short* ab    = (unsigned short*)(ws + 40 * MB);  // 8MB  [4096][1024]

  cast_bf16<<<dim3(Mv * Cv / (256 * 8)), dim3(256), 0, stream>>>(x, xb);
  transcast<<<dim3(3072 / 32, 1024 / 32), dim3(256), 0, stream>>>(w_qkv, wqkvT, 1024, 3072);
  transcast<<<dim3(1024 / 32, 1024 / 32), dim3(256), 0, stream>>>(w_out, woutT, 1024, 1024);
  gemm128<0><<<dim3(3072 / 128, Mv / 128), dim3(256), 0, stream>>>(
      xb, wqkvT, nullptr, qb, kb, vTb, 3072);
  flash_attn<<<dim3(16, Bv * Hv), dim3(256), 0, stream>>>(qb, kb, vTb, ab);
  gemm128<1><<<dim3(Cv / 128, Mv / 128), dim3(256), 0, stream>>>(
      ab, woutT, out, nullptr, nullptr, nullptr, Cv);
}

// Round 4
// 157.797 us; speedup vs baseline: 1.7777x; 1.0262x over previous
//
#include <hip/hip_runtime.h>
#include <hip/hip_bf16.h>
#include <stdint.h>

// B=2, T=2048, C=1024, H=16, D=64
// out = ( causal_attn(x@Wqkv) ) @ Wout
// bf16 MFMA pipeline, f32 accumulate everywhere.
// R4: native (__bf16) casts everywhere (HW v_cvt, not manual RNE bit-ops);
// T13 defer-max rescale in flash (wave-voted, P bounded by 2^8).

#define Bv 2
#define Tv 2048
#define Cv 1024
#define Hv 16
#define Dv 64
#define Mv 4096  // B*T

typedef __attribute__((ext_vector_type(8))) __bf16 bf16x8;
typedef __attribute__((ext_vector_type(4))) float f32x4;
typedef __attribute__((ext_vector_type(4))) unsigned short ushort4v;

__device__ __forceinline__ unsigned short f2bs(float f) {
  union { __bf16 h; unsigned short s; } u;
  u.h = (__bf16)f;  // native HW cvt (RNE on gfx950)
  return u.s;
}

__device__ __forceinline__ void gload16(const void* g, void* l) {
  __builtin_amdgcn_global_load_lds(
      (__attribute__((address_space(1))) void*)(uintptr_t)g,
      (__attribute__((address_space(3))) void*)(unsigned int)(uintptr_t)l,
      16, 0, 0);
}

__device__ __forceinline__ bf16x8 ldfrag(const unsigned short* p) {
  return *reinterpret_cast<const bf16x8*>(p);
}

// ---------------- cast f32 -> bf16, 8 elems/thread ----------------
__global__ void __launch_bounds__(256) cast_bf16(const float* __restrict__ in,
                                                 unsigned short* __restrict__ out) {
  int i = (blockIdx.x * 256 + threadIdx.x) * 8;
  float4 a = *reinterpret_cast<const float4*>(in + i);
  float4 b = *reinterpret_cast<const float4*>(in + i + 4);
  ushort4v o0, o1;
  o0.x = f2bs(a.x); o0.y = f2bs(a.y); o0.z = f2bs(a.z); o0.w = f2bs(a.w);
  o1.x = f2bs(b.x); o1.y = f2bs(b.y); o1.z = f2bs(b.z); o1.w = f2bs(b.w);
  *reinterpret_cast<ushort4v*>(out + i) = o0;
  *reinterpret_cast<ushort4v*>(out + i + 4) = o1;
}

// ---------------- transpose + cast: in f32 [R][Cc] -> out bf16 [Cc][R] ----------------
__global__ void __launch_bounds__(256) transcast(const float* __restrict__ in,
                                                 unsigned short* __restrict__ out,
                                                 int R, int Cc) {
  __shared__ float tile[32][33];
  int c0 = blockIdx.x * 32;
  int r0 = blockIdx.y * 32;
  int tc = threadIdx.x & 31, tr = threadIdx.x >> 5;
#pragma unroll
  for (int i = 0; i < 4; i++)
    tile[tr + i * 8][tc] = in[(size_t)(r0 + tr + i * 8) * Cc + c0 + tc];
  __syncthreads();
#pragma unroll
  for (int i = 0; i < 4; i++)
    out[(size_t)(c0 + tr + i * 8) * R + r0 + tc] = f2bs(tile[tc][tr + i * 8]);
}

// ---------------- GEMM: C[M][N] = A[M][1024] * Bt[N][1024]^T ----------------
// 128x128 tile, BK=32, 256 threads (2x2 waves, each 64x64 = 4x4 MFMA frags).
// Double-buffered LDS, ONE __syncthreads per K-step.
template <int EPI>
__global__ void __launch_bounds__(256) gemm128(
    const unsigned short* __restrict__ A, const unsigned short* __restrict__ Bt,
    float* __restrict__ outF, unsigned short* __restrict__ qo,
    unsigned short* __restrict__ ko, unsigned short* __restrict__ vTo, int N) {
  __shared__ unsigned short la[2][4][128][8];
  __shared__ unsigned short lb[2][4][128][8];
  const int K = 1024;
  int mb = blockIdx.y * 128, nb = blockIdx.x * 128;
  int tid = threadIdx.x;
  int l = tid & 63, w = tid >> 6;
  int wr = w >> 1, wc = w & 1;
  int lr = l & 15, lg = l >> 4;
  f32x4 acc[4][4] = {};
  int c0 = tid >> 7, r0 = tid & 127;

  auto STAGE = [&](int kb, int buf) {
    gload16(A + (size_t)(mb + r0) * K + kb + c0 * 8, &la[buf][c0][r0][0]);
    gload16(A + (size_t)(mb + r0) * K + kb + (c0 + 2) * 8, &la[buf][c0 + 2][r0][0]);
    gload16(Bt + (size_t)(nb + r0) * K + kb + c0 * 8, &lb[buf][c0][r0][0]);
    gload16(Bt + (size_t)(nb + r0) * K + kb + (c0 + 2) * 8, &lb[buf][c0 + 2][r0][0]);
  };

  STAGE(0, 0);
  int cur = 0;
  for (int kb = 0; kb < K; kb += 32) {
    __syncthreads();
    if (kb + 32 < K) STAGE(kb + 32, cur ^ 1);
    bf16x8 af[4], bfr[4];
#pragma unroll
    for (int mi = 0; mi < 4; mi++) af[mi] = ldfrag(&la[cur][lg][wr * 64 + mi * 16 + lr][0]);
#pragma unroll
    for (int ni = 0; ni < 4; ni++) bfr[ni] = ldfrag(&lb[cur][lg][wc * 64 + ni * 16 + lr][0]);
#pragma unroll
    for (int mi = 0; mi < 4; mi++)
#pragma unroll
      for (int ni = 0; ni < 4; ni++)
        acc[mi][ni] = __builtin_amdgcn_mfma_f32_16x16x32_bf16(af[mi], bfr[ni], acc[mi][ni], 0, 0, 0);
    cur ^= 1;
  }

#pragma unroll
  for (int mi = 0; mi < 4; mi++) {
#pragma unroll
    for (int ni = 0; ni < 4; ni++) {
      int row0 = mb + wr * 64 + mi * 16 + lg * 4;
      int col = nb + wc * 64 + ni * 16 + lr;
      if (EPI == 1) {
#pragma unroll
        for (int r = 0; r < 4; r++)
          outF[(size_t)(row0 + r) * N + col] = acc[mi][ni][r];
      } else {
        int which = col >> 10, cc = col & 1023;
        int h = cc >> 6, d = cc & 63;
        int bb = row0 >> 11, t = row0 & 2047;
        size_t bh = (size_t)bb * Hv + h;
        if (which == 0) {
#pragma unroll
          for (int r = 0; r < 4; r++)
            qo[(bh * Tv + t + r) * Dv + d] = f2bs(acc[mi][ni][r]);
        } else if (which == 1) {
#pragma unroll
          for (int r = 0; r < 4; r++)
            ko[(bh * Tv + t + r) * Dv + d] = f2bs(acc[mi][ni][r]);
        } else {  // v stored transposed [B,H,D,T]
          ushort4v pk;
#pragma unroll
          for (int r = 0; r < 4; r++) pk[r] = f2bs(acc[mi][ni][r]);
          *reinterpret_cast<ushort4v*>(&vTo[(bh * Dv + d) * Tv + t]) = pk;
        }
      }
    }
  }
}

// ---------------- flash attention ----------------
// grid (pair=16, bh=32), 256 threads = 4 waves; each wave owns 16 q-rows.
// Each block processes q-tiles {i, 31-i} sequentially -> uniform 33 K-tiles.
// KT=64, double-buffered K/V, one __syncthreads per tile.
// Row-sum via MFMA ones-trick; row-max via shfl_xor; T13 defer-max rescale.
__global__ void __launch_bounds__(256) flash_attn(
    const unsigned short* __restrict__ Q, const unsigned short* __restrict__ Kk,
    const unsigned short* __restrict__ Vt, unsigned short* __restrict__ O) {
  __shared__ unsigned short lK[2][8][64][8];  // 16KB
  __shared__ unsigned short lV[2][8][64][8];  // 16KB
  __shared__ unsigned short lP[4][16][72];    // 9KB, wave-private slabs
  int bh = blockIdx.y;
  int b = bh >> 4, h = bh & 15;
  int tid = threadIdx.x;
  int l = tid & 63, w = tid >> 6;
  int lr = l & 15, lg = l >> 4;
  const unsigned short* Qp = Q + (size_t)bh * Tv * Dv;
  const unsigned short* Kp = Kk + (size_t)bh * Tv * Dv;
  const unsigned short* Vp = Vt + (size_t)bh * Dv * Tv;
  const float Cs = 0.125f * 1.4426950408889634f;  // scale * log2(e)
  const float THRraw = 8.0f / Cs;                 // defer-max threshold (P <= 2^8)
  const __bf16 kOne = (__bf16)1.0f;
  const bf16x8 vone = {kOne, kOne, kOne, kOne, kOne, kOne, kOne, kOne};
  int sr = tid & 63, sc = tid >> 6;  // staging: row, chunk-base

  for (int ph = 0; ph < 2; ++ph) {
    int qt = ph ? (31 - (int)blockIdx.x) : (int)blockIdx.x;
    int q0 = qt * 64;
    int nt = qt + 1;
    int qrow = q0 + w * 16 + lr;
    bf16x8 qf0 = ldfrag(&Qp[(size_t)qrow * Dv + lg * 8]);
    bf16x8 qf1 = ldfrag(&Qp[(size_t)qrow * Dv + 32 + lg * 8]);
    f32x4 o[4] = {};
    float mrow[4], lsum[4];
#pragma unroll
    for (int r = 0; r < 4; r++) { mrow[r] = -1e30f; lsum[r] = 0.f; }

    auto STAGE = [&](int it, int buf) {
      int k0 = it * 64;
      gload16(Kp + (size_t)(k0 + sr) * Dv + sc * 8, &lK[buf][sc][sr][0]);
      gload16(Kp + (size_t)(k0 + sr) * Dv + (sc + 4) * 8, &lK[buf][sc + 4][sr][0]);
      gload16(Vp + (size_t)sr * Tv + k0 + sc * 8, &lV[buf][sc][sr][0]);
      gload16(Vp + (size_t)sr * Tv + k0 + (sc + 4) * 8, &lV[buf][sc + 4][sr][0]);
    };

    if (ph) __syncthreads();  // protect LDS reuse across the phase boundary
    STAGE(0, 0);
    int cur = 0;
    for (int it = 0; it < nt; ++it) {
      __syncthreads();  // drains prefetch of tile `it` + protects buffer reuse
      if (it + 1 < nt) STAGE(it + 1, cur ^ 1);
      int k0 = it * 64;
      // S = Q K^T : 4 column blocks of 16 keys, C-layout (row = lg*4+r, col = lr)
      f32x4 s[4] = {};
#pragma unroll
      for (int j = 0; j < 4; ++j) {
        bf16x8 kf0 = ldfrag(&lK[cur][lg][j * 16 + lr][0]);
        s[j] = __builtin_amdgcn_mfma_f32_16x16x32_bf16(qf0, kf0, s[j], 0, 0, 0);
        bf16x8 kf1 = ldfrag(&lK[cur][4 + lg][j * 16 + lr][0]);
        s[j] = __builtin_amdgcn_mfma_f32_16x16x32_bf16(qf1, kf1, s[j], 0, 0, 0);
      }
      int qg0 = q0 + w * 16 + lg * 4;
      if (it == nt - 1) {  // diagonal tile only
#pragma unroll
        for (int j = 0; j < 4; ++j)
#pragma unroll
          for (int r = 0; r < 4; ++r)
            if (k0 + j * 16 + lr > qg0 + r) s[j][r] = -1e30f;
      }
      // row max of this tile (shaped for v_max3 fusion)
      float pmax[4];
#pragma unroll
      for (int r = 0; r < 4; ++r) {
        float v = fmaxf(fmaxf(fmaxf(s[0][r], s[1][r]), s[2][r]), s[3][r]);
        v = fmaxf(v, __shfl_xor(v, 1));
        v = fmaxf(v, __shfl_xor(v, 2));
        v = fmaxf(v, __shfl_xor(v, 4));
        v = fmaxf(v, __shfl_xor(v, 8));
        pmax[r] = v;
      }
      // T13 defer-max: rescale only when some row's max grew past threshold
      bool need = false;
#pragma unroll
      for (int r = 0; r < 4; ++r) need = need || (pmax[r] > mrow[r] + THRraw);
      if (__any(need)) {
#pragma unroll
        for (int r = 0; r < 4; ++r) {
          float mn = fmaxf(mrow[r], pmax[r]);
          float al = exp2f((mrow[r] - mn) * Cs);
          mrow[r] = mn;
          lsum[r] *= al;
#pragma unroll
          for (int nb = 0; nb < 4; ++nb) o[nb][r] *= al;
        }
      }
#pragma unroll
      for (int r = 0; r < 4; ++r) {
        lP[w][lg * 4 + r][lr]      = f2bs(exp2f((s[0][r] - mrow[r]) * Cs));
        lP[w][lg * 4 + r][16 + lr] = f2bs(exp2f((s[1][r] - mrow[r]) * Cs));
        lP[w][lg * 4 + r][32 + lr] = f2bs(exp2f((s[2][r] - mrow[r]) * Cs));
        lP[w][lg * 4 + r][48 + lr] = f2bs(exp2f((s[3][r] - mrow[r]) * Cs));
      }
      // PV + row-sum: A = P (wave-private LDS), B = V^T tile / ones
      f32x4 srow = {0.f, 0.f, 0.f, 0.f};
#pragma unroll
      for (int kk = 0; kk < 2; ++kk) {
        bf16x8 pf = ldfrag(&lP[w][lr][kk * 32 + lg * 8]);
        srow = __builtin_amdgcn_mfma_f32_16x16x32_bf16(pf, vone, srow, 0, 0, 0);
#pragma unroll
        for (int nb = 0; nb < 4; ++nb) {
          bf16x8 vf = ldfrag(&lV[cur][kk * 4 + lg][nb * 16 + lr][0]);
          o[nb] = __builtin_amdgcn_mfma_f32_16x16x32_bf16(pf, vf, o[nb], 0, 0, 0);
        }
      }
#pragma unroll
      for (int r = 0; r < 4; ++r) lsum[r] += srow[r];
      cur ^= 1;
    }
    // epilogue: normalize, write [B,T,H*D] bf16
#pragma unroll
    for (int r = 0; r < 4; ++r) {
      int t = q0 + w * 16 + lg * 4 + r;
      float inv = 1.0f / lsum[r];
      size_t rowbase = ((size_t)b * Tv + t) * Cv + h * Dv;
#pragma unroll
      for (int nb = 0; nb < 4; ++nb)
        O[rowbase + nb * 16 + lr] = f2bs(o[nb][r] * inv);
    }
  }
}

// ---------------- host ----------------
extern "C" void kernel_launch(void* const* d_in, const int* in_sizes, int n_in,
                              void* d_out, int out_size, void* d_ws, size_t ws_size,
                              hipStream_t stream) {
  const float* x = (const float*)d_in[0];      // [2,2048,1024]
  const float* w_qkv = (const float*)d_in[1];  // [1024,3072]
  const float* w_out = (const float*)d_in[2];  // [1024,1024]
  float* out = (float*)d_out;                  // [2,2048,1024] f32
  char* ws = (char*)d_ws;
  const size_t MB = 1u << 20;
  unsigned short* xb    = (unsigned short*)(ws + 0);        // 8MB  [4096][1024]
  unsigned short* wqkvT = (unsigned short*)(ws + 8 * MB);   // 6MB  [3072][1024]
  unsigned short* woutT = (unsigned short*)(ws + 14 * MB);  // 2MB  [1024][1024]
  unsigned short* qb    = (unsigned short*)(ws + 16 * MB);  // 8MB  [B,H,T,D]
  unsigned short* kb    = (unsigned short*)(ws + 24 * MB);  // 8MB  [B,H,T,D]
  unsigned short* vTb   = (unsigned short*)(ws + 32 * MB);  // 8MB  [B,H,D,T]
  unsigned short* ab    = (unsigned short*)(ws + 40 * MB);  // 8MB  [4096][1024]

  cast_bf16<<<dim3(Mv * Cv / (256 * 8)), dim3(256), 0, stream>>>(x, xb);
  transcast<<<dim3(3072 / 32, 1024 / 32), dim3(256), 0, stream>>>(w_qkv, wqkvT, 1024, 3072);
  transcast<<<dim3(1024 / 32, 1024 / 32), dim3(256), 0, stream>>>(w_out, woutT, 1024, 1024);
  gemm128<0><<<dim3(3072 / 128, Mv / 128), dim3(256), 0, stream>>>(
      xb, wqkvT, nullptr, qb, kb, vTb, 3072);
  flash_attn<<<dim3(16, Bv * Hv), dim3(256), 0, stream>>>(qb, kb, vTb, ab);
  gemm128<1><<<dim3(Cv / 128, Mv / 128), dim3(256), 0, stream>>>(
      ab, woutT, out, nullptr, nullptr, nullptr, Cv);
}

// Round 5
// 148.440 us; speedup vs baseline: 1.8898x; 1.0630x over previous
//
#include <hip/hip_runtime.h>
#include <hip/hip_bf16.h>
#include <stdint.h>

// B=2, T=2048, C=1024, H=16, D=64
// out = ( causal_attn(x@Wqkv) ) @ Wout
// bf16 MFMA pipeline, f32 accumulate everywhere.
// R5: flash uses swapped QK^T (S^T = mfma(K, Q^T)) so each lane owns 16 keys
// of ONE q-row: row-max = 15 fmax + 2 shfl (was 16 shfl), P-store = 4x
// ds_write_b64 (was 16x ds_write_b16). mrow scalar in lr-domain; lsum stays
// rho-domain via ones-MFMA; rescale crosses domains via 4 shfl on rare events.

#define Bv 2
#define Tv 2048
#define Cv 1024
#define Hv 16
#define Dv 64
#define Mv 4096  // B*T

typedef __attribute__((ext_vector_type(8))) __bf16 bf16x8;
typedef __attribute__((ext_vector_type(4))) float f32x4;
typedef __attribute__((ext_vector_type(4))) unsigned short ushort4v;

__device__ __forceinline__ unsigned short f2bs(float f) {
  union { __bf16 h; unsigned short s; } u;
  u.h = (__bf16)f;  // native HW cvt (RNE on gfx950)
  return u.s;
}

__device__ __forceinline__ void gload16(const void* g, void* l) {
  __builtin_amdgcn_global_load_lds(
      (__attribute__((address_space(1))) void*)(uintptr_t)g,
      (__attribute__((address_space(3))) void*)(unsigned int)(uintptr_t)l,
      16, 0, 0);
}

__device__ __forceinline__ bf16x8 ldfrag(const unsigned short* p) {
  return *reinterpret_cast<const bf16x8*>(p);
}

// ---------------- cast f32 -> bf16, 8 elems/thread ----------------
__global__ void __launch_bounds__(256) cast_bf16(const float* __restrict__ in,
                                                 unsigned short* __restrict__ out) {
  int i = (blockIdx.x * 256 + threadIdx.x) * 8;
  float4 a = *reinterpret_cast<const float4*>(in + i);
  float4 b = *reinterpret_cast<const float4*>(in + i + 4);
  ushort4v o0, o1;
  o0.x = f2bs(a.x); o0.y = f2bs(a.y); o0.z = f2bs(a.z); o0.w = f2bs(a.w);
  o1.x = f2bs(b.x); o1.y = f2bs(b.y); o1.z = f2bs(b.z); o1.w = f2bs(b.w);
  *reinterpret_cast<ushort4v*>(out + i) = o0;
  *reinterpret_cast<ushort4v*>(out + i + 4) = o1;
}

// ---------------- transpose + cast: in f32 [R][Cc] -> out bf16 [Cc][R] ----------------
__global__ void __launch_bounds__(256) transcast(const float* __restrict__ in,
                                                 unsigned short* __restrict__ out,
                                                 int R, int Cc) {
  __shared__ float tile[32][33];
  int c0 = blockIdx.x * 32;
  int r0 = blockIdx.y * 32;
  int tc = threadIdx.x & 31, tr = threadIdx.x >> 5;
#pragma unroll
  for (int i = 0; i < 4; i++)
    tile[tr + i * 8][tc] = in[(size_t)(r0 + tr + i * 8) * Cc + c0 + tc];
  __syncthreads();
#pragma unroll
  for (int i = 0; i < 4; i++)
    out[(size_t)(c0 + tr + i * 8) * R + r0 + tc] = f2bs(tile[tc][tr + i * 8]);
}

// ---------------- GEMM: C[M][N] = A[M][1024] * Bt[N][1024]^T ----------------
// 128x128 tile, BK=32, 256 threads (2x2 waves, each 64x64 = 4x4 MFMA frags).
// Double-buffered LDS, ONE __syncthreads per K-step.
template <int EPI>
__global__ void __launch_bounds__(256) gemm128(
    const unsigned short* __restrict__ A, const unsigned short* __restrict__ Bt,
    float* __restrict__ outF, unsigned short* __restrict__ qo,
    unsigned short* __restrict__ ko, unsigned short* __restrict__ vTo, int N) {
  __shared__ unsigned short la[2][4][128][8];
  __shared__ unsigned short lb[2][4][128][8];
  const int K = 1024;
  int mb = blockIdx.y * 128, nb = blockIdx.x * 128;
  int tid = threadIdx.x;
  int l = tid & 63, w = tid >> 6;
  int wr = w >> 1, wc = w & 1;
  int lr = l & 15, lg = l >> 4;
  f32x4 acc[4][4] = {};
  int c0 = tid >> 7, r0 = tid & 127;

  auto STAGE = [&](int kb, int buf) {
    gload16(A + (size_t)(mb + r0) * K + kb + c0 * 8, &la[buf][c0][r0][0]);
    gload16(A + (size_t)(mb + r0) * K + kb + (c0 + 2) * 8, &la[buf][c0 + 2][r0][0]);
    gload16(Bt + (size_t)(nb + r0) * K + kb + c0 * 8, &lb[buf][c0][r0][0]);
    gload16(Bt + (size_t)(nb + r0) * K + kb + (c0 + 2) * 8, &lb[buf][c0 + 2][r0][0]);
  };

  STAGE(0, 0);
  int cur = 0;
  for (int kb = 0; kb < K; kb += 32) {
    __syncthreads();
    if (kb + 32 < K) STAGE(kb + 32, cur ^ 1);
    bf16x8 af[4], bfr[4];
#pragma unroll
    for (int mi = 0; mi < 4; mi++) af[mi] = ldfrag(&la[cur][lg][wr * 64 + mi * 16 + lr][0]);
#pragma unroll
    for (int ni = 0; ni < 4; ni++) bfr[ni] = ldfrag(&lb[cur][lg][wc * 64 + ni * 16 + lr][0]);
#pragma unroll
    for (int mi = 0; mi < 4; mi++)
#pragma unroll
      for (int ni = 0; ni < 4; ni++)
        acc[mi][ni] = __builtin_amdgcn_mfma_f32_16x16x32_bf16(af[mi], bfr[ni], acc[mi][ni], 0, 0, 0);
    cur ^= 1;
  }

#pragma unroll
  for (int mi = 0; mi < 4; mi++) {
#pragma unroll
    for (int ni = 0; ni < 4; ni++) {
      int row0 = mb + wr * 64 + mi * 16 + lg * 4;
      int col = nb + wc * 64 + ni * 16 + lr;
      if (EPI == 1) {
#pragma unroll
        for (int r = 0; r < 4; r++)
          outF[(size_t)(row0 + r) * N + col] = acc[mi][ni][r];
      } else {
        int which = col >> 10, cc = col & 1023;
        int h = cc >> 6, d = cc & 63;
        int bb = row0 >> 11, t = row0 & 2047;
        size_t bh = (size_t)bb * Hv + h;
        if (which == 0) {
#pragma unroll
          for (int r = 0; r < 4; r++)
            qo[(bh * Tv + t + r) * Dv + d] = f2bs(acc[mi][ni][r]);
        } else if (which == 1) {
#pragma unroll
          for (int r = 0; r < 4; r++)
            ko[(bh * Tv + t + r) * Dv + d] = f2bs(acc[mi][ni][r]);
        } else {  // v stored transposed [B,H,D,T]
          ushort4v pk;
#pragma unroll
          for (int r = 0; r < 4; r++) pk[r] = f2bs(acc[mi][ni][r]);
          *reinterpret_cast<ushort4v*>(&vTo[(bh * Dv + d) * Tv + t]) = pk;
        }
      }
    }
  }
}

// ---------------- flash attention ----------------
// grid (pair=16, bh=32), 256 threads = 4 waves; each wave owns 16 q-rows.
// Each block processes q-tiles {i, 31-i} sequentially -> uniform 33 K-tiles.
// KT=64, double-buffered K/V, one __syncthreads per tile.
// Swapped QK^T; packed b64 P-stores; ones-MFMA row-sum; T13 defer-max.
__global__ void __launch_bounds__(256) flash_attn(
    const unsigned short* __restrict__ Q, const unsigned short* __restrict__ Kk,
    const unsigned short* __restrict__ Vt, unsigned short* __restrict__ O) {
  __shared__ unsigned short lK[2][8][64][8];  // 16KB
  __shared__ unsigned short lV[2][8][64][8];  // 16KB
  __shared__ unsigned short lP[4][16][72];    // 9KB, wave-private slabs
  int bh = blockIdx.y;
  int b = bh >> 4, h = bh & 15;
  int tid = threadIdx.x;
  int l = tid & 63, w = tid >> 6;
  int lr = l & 15, lg = l >> 4;
  const unsigned short* Qp = Q + (size_t)bh * Tv * Dv;
  const unsigned short* Kp = Kk + (size_t)bh * Tv * Dv;
  const unsigned short* Vp = Vt + (size_t)bh * Dv * Tv;
  const float Cs = 0.125f * 1.4426950408889634f;  // scale * log2(e)
  const float THRraw = 8.0f / Cs;                 // defer-max threshold (P <= 2^8)
  const __bf16 kOne = (__bf16)1.0f;
  const bf16x8 vone = {kOne, kOne, kOne, kOne, kOne, kOne, kOne, kOne};
  int sr = tid & 63, sc = tid >> 6;  // staging: row, chunk-base

  for (int ph = 0; ph < 2; ++ph) {
    int qt = ph ? (31 - (int)blockIdx.x) : (int)blockIdx.x;
    int q0 = qt * 64;
    int nt = qt + 1;
    int qrow = q0 + w * 16 + lr;
    bf16x8 qf0 = ldfrag(&Qp[(size_t)qrow * Dv + lg * 8]);
    bf16x8 qf1 = ldfrag(&Qp[(size_t)qrow * Dv + 32 + lg * 8]);
    f32x4 o[4] = {};
    f32x4 lsum = {0.f, 0.f, 0.f, 0.f};  // rho-domain (row = lg*4+r)
    float mrow = -1e30f;                // lr-domain scalar (row = lr)

    auto STAGE = [&](int it, int buf) {
      int k0 = it * 64;
      gload16(Kp + (size_t)(k0 + sr) * Dv + sc * 8, &lK[buf][sc][sr][0]);
      gload16(Kp + (size_t)(k0 + sr) * Dv + (sc + 4) * 8, &lK[buf][sc + 4][sr][0]);
      gload16(Vp + (size_t)sr * Tv + k0 + sc * 8, &lV[buf][sc][sr][0]);
      gload16(Vp + (size_t)sr * Tv + k0 + (sc + 4) * 8, &lV[buf][sc + 4][sr][0]);
    };

    if (ph) __syncthreads();  // protect LDS reuse across the phase boundary
    STAGE(0, 0);
    int cur = 0;
    for (int it = 0; it < nt; ++it) {
      __syncthreads();  // drains prefetch of tile `it` + protects buffer reuse
      if (it + 1 < nt) STAGE(it + 1, cur ^ 1);
      int k0 = it * 64;
      // S^T = K Q^T : 4 row blocks of 16 keys. C-layout: col=lr is the q-row,
      // row=lg*4+r is the key. Operand reads identical to the unswapped form.
      f32x4 s[4] = {};
#pragma unroll
      for (int j = 0; j < 4; ++j) {
        bf16x8 kf0 = ldfrag(&lK[cur][lg][j * 16 + lr][0]);
        s[j] = __builtin_amdgcn_mfma_f32_16x16x32_bf16(kf0, qf0, s[j], 0, 0, 0);
        bf16x8 kf1 = ldfrag(&lK[cur][4 + lg][j * 16 + lr][0]);
        s[j] = __builtin_amdgcn_mfma_f32_16x16x32_bf16(kf1, qf1, s[j], 0, 0, 0);
      }
      // NOTE: in S^T, lane (lg,lr) holds keys {k0+16j+4lg+r} for q-row lr.
      int qg = q0 + w * 16 + lr;
      if (it == nt - 1) {  // diagonal tile only
#pragma unroll
        for (int j = 0; j < 4; ++j)
#pragma unroll
          for (int r = 0; r < 4; ++r)
            if (k0 + j * 16 + lg * 4 + r > qg) s[j][r] = -1e30f;
      }
      // tile max of q-row lr: 15 local fmax + 2 shuffles across lg
      float v = fmaxf(fmaxf(fmaxf(s[0][0], s[0][1]), fmaxf(s[0][2], s[0][3])),
                      fmaxf(fmaxf(s[1][0], s[1][1]), fmaxf(s[1][2], s[1][3])));
      v = fmaxf(v, fmaxf(fmaxf(fmaxf(s[2][0], s[2][1]), fmaxf(s[2][2], s[2][3])),
                         fmaxf(fmaxf(s[3][0], s[3][1]), fmaxf(s[3][2], s[3][3]))));
      v = fmaxf(v, __shfl_xor(v, 16));
      v = fmaxf(v, __shfl_xor(v, 32));
      // T13 defer-max: rescale only when this row's max grew past threshold
      if (__any(v > mrow + THRraw)) {
        float mn = fmaxf(mrow, v);
        float al = exp2f((mrow - mn) * Cs);  // lr-domain
        mrow = mn;
#pragma unroll
        for (int r = 0; r < 4; ++r) {  // cross to rho-domain (4 shfl, rare)
          float alr = __shfl(al, (l & 48) | (lg * 4 + r));
          lsum[r] *= alr;
#pragma unroll
          for (int nb = 0; nb < 4; ++nb) o[nb][r] *= alr;
        }
      }
      // P = exp2((S - m)*Cs), packed 4 consecutive keys -> one ds_write_b64
#pragma unroll
      for (int j = 0; j < 4; ++j) {
        ushort4v pk;
#pragma unroll
        for (int r = 0; r < 4; ++r) pk[r] = f2bs(exp2f((s[j][r] - mrow) * Cs));
        *reinterpret_cast<ushort4v*>(&lP[w][lr][j * 16 + lg * 4]) = pk;
      }
      // PV + row-sum: A = P (wave-private LDS), B = V^T tile / ones
      f32x4 srow = {0.f, 0.f, 0.f, 0.f};
#pragma unroll
      for (int kk = 0; kk < 2; ++kk) {
        bf16x8 pf = ldfrag(&lP[w][lr][kk * 32 + lg * 8]);
        srow = __builtin_amdgcn_mfma_f32_16x16x32_bf16(pf, vone, srow, 0, 0, 0);
#pragma unroll
        for (int nb = 0; nb < 4; ++nb) {
          bf16x8 vf = ldfrag(&lV[cur][kk * 4 + lg][nb * 16 + lr][0]);
          o[nb] = __builtin_amdgcn_mfma_f32_16x16x32_bf16(pf, vf, o[nb], 0, 0, 0);
        }
      }
#pragma unroll
      for (int r = 0; r < 4; ++r) lsum[r] += srow[r];
      cur ^= 1;
    }
    // epilogue: normalize, write [B,T,H*D] bf16 (rho-domain rows)
#pragma unroll
    for (int r = 0; r < 4; ++r) {
      int t = q0 + w * 16 + lg * 4 + r;
      float inv = 1.0f / lsum[r];
      size_t rowbase = ((size_t)b * Tv + t) * Cv + h * Dv;
#pragma unroll
      for (int nb = 0; nb < 4; ++nb)
        O[rowbase + nb * 16 + lr] = f2bs(o[nb][r] * inv);
    }
  }
}

// ---------------- host ----------------
extern "C" void kernel_launch(void* const* d_in, const int* in_sizes, int n_in,
                              void* d_out, int out_size, void* d_ws, size_t ws_size,
                              hipStream_t stream) {
  const float* x = (const float*)d_in[0];      // [2,2048,1024]
  const float* w_qkv = (const float*)d_in[1];  // [1024,3072]
  const float* w_out = (const float*)d_in[2];  // [1024,1024]
  float* out = (float*)d_out;                  // [2,2048,1024] f32
  char* ws = (char*)d_ws;
  const size_t MB = 1u << 20;
  unsigned short* xb    = (unsigned short*)(ws + 0);        // 8MB  [4096][1024]
  unsigned short* wqkvT = (unsigned short*)(ws + 8 * MB);   // 6MB  [3072][1024]
  unsigned short* woutT = (unsigned short*)(ws + 14 * MB);  // 2MB  [1024][1024]
  unsigned short* qb    = (unsigned short*)(ws + 16 * MB);  // 8MB  [B,H,T,D]
  unsigned short* kb    = (unsigned short*)(ws + 24 * MB);  // 8MB  [B,H,T,D]
  unsigned short* vTb   = (unsigned short*)(ws + 32 * MB);  // 8MB  [B,H,D,T]
  unsigned short* ab    = (unsigned short*)(ws + 40 * MB);  // 8MB  [4096][1024]

  cast_bf16<<<dim3(Mv * Cv / (256 * 8)), dim3(256), 0, stream>>>(x, xb);
  transcast<<<dim3(3072 / 32, 1024 / 32), dim3(256), 0, stream>>>(w_qkv, wqkvT, 1024, 3072);
  transcast<<<dim3(1024 / 32, 1024 / 32), dim3(256), 0, stream>>>(w_out, woutT, 1024, 1024);
  gemm128<0><<<dim3(3072 / 128, Mv / 128), dim3(256), 0, stream>>>(
      xb, wqkvT, nullptr, qb, kb, vTb, 3072);
  flash_attn<<<dim3(16, Bv * Hv), dim3(256), 0, stream>>>(qb, kb, vTb, ab);
  gemm128<1><<<dim3(Cv / 128, Mv / 128), dim3(256), 0, stream>>>(
      ab, woutT, out, nullptr, nullptr, nullptr, Cv);
}